// Round 1
// baseline (8684.044 us; speedup 1.0000x reference)
//
#include <hip/hip_runtime.h>

// LSTM: T=512, B=32, H=512, L=2.  fp16 compute, fp32 accumulate/state.
// Phase A (per layer): x_proj = x @ Wih^T + bih + bhh   (GEMM 16384x2048x512, MFMA fp16)
// Phase B (per layer): sequential recurrence, 32 persistent WGs, flag-based sync.

typedef _Float16 half8_t __attribute__((ext_vector_type(8)));
typedef _Float16 half4_t __attribute__((ext_vector_type(4)));
typedef float f32x4 __attribute__((ext_vector_type(4)));
typedef unsigned int u32;

#define T_LEN 512
#define BATCH 32
#define HID 512
#define GATES4 2048   // 4*HID
#define KDIM 512

__device__ __forceinline__ void async_copy16(const void* gsrc, void* ldst) {
  __builtin_amdgcn_global_load_lds(
      (const __attribute__((address_space(1))) u32*)gsrc,
      (__attribute__((address_space(3))) u32*)ldst,
      16, 0, 0);
}

// ---------------- convert fp32 -> fp16 (x, Wih, Whh) + bias sum ----------------
__global__ __launch_bounds__(256) void convert_k(
    const float4* __restrict__ x,    // 8388608 floats = 2097152 float4
    const float4* __restrict__ wih,  // 2097152 floats = 524288 float4
    const float4* __restrict__ whh,  // same
    const float* __restrict__ bih, const float* __restrict__ bhh,
    half4_t* __restrict__ xh, half4_t* __restrict__ wihh, half4_t* __restrict__ whhh,
    float* __restrict__ bsum) {
  const int N4X = 2097152, N4W = 524288, TOT = N4X + 2 * N4W;
  int gid = blockIdx.x * 256 + threadIdx.x;
  for (int i = gid; i < TOT; i += gridDim.x * 256) {
    float4 v;
    half4_t* dst;
    if (i < N4X) { v = x[i]; dst = xh + i; }
    else if (i < N4X + N4W) { v = wih[i - N4X]; dst = wihh + (i - N4X); }
    else { v = whh[i - N4X - N4W]; dst = whhh + (i - N4X - N4W); }
    half4_t h;
    h[0] = (_Float16)v.x; h[1] = (_Float16)v.y; h[2] = (_Float16)v.z; h[3] = (_Float16)v.w;
    *dst = h;
  }
  if (gid < 2 * GATES4) bsum[gid] = bih[gid] + bhh[gid];
}

// ---------------- GEMM: C[M=16384][2048] = A[M][512] @ W[2048][512]^T + bias ----
// 128x128 tile, BK=64, 4 waves each 64x64 (4x4 of 16x16x32 mfma).
// LDS chunk swizzle: logical 16B chunk kg of row m stored at phys chunk kg^(m&7).
__global__ __launch_bounds__(256) void gemm_xproj(
    const _Float16* __restrict__ A, const _Float16* __restrict__ W,
    const float* __restrict__ bias, _Float16* __restrict__ C) {
  __shared__ _Float16 As[128 * 64];
  __shared__ _Float16 Bs[128 * 64];
  const int K = KDIM;
  int bx = blockIdx.x;
  int tn = bx & 15, tm = bx >> 4;
  int m0 = tm * 128, n0 = tn * 128;
  int tid = threadIdx.x, wv = tid >> 6, ln = tid & 63;
  int wm = wv & 1, wn = wv >> 1;
  int q = ln >> 4, cc = ln & 15;
  f32x4 acc[4][4] = {};
  for (int k0 = 0; k0 < K; k0 += 64) {
    for (int j = 0; j < 4; ++j) {
      int p = (wv * 4 + j) * 64 + ln;
      int m = p >> 3, pc = p & 7, kg = pc ^ (m & 7);
      async_copy16(A + (size_t)(m0 + m) * K + k0 + kg * 8, (void*)(As + (p - ln) * 8));
      async_copy16(W + (size_t)(n0 + m) * K + k0 + kg * 8, (void*)(Bs + (p - ln) * 8));
    }
    __syncthreads();
    for (int kc = 0; kc < 2; ++kc) {
      half8_t af[4], bf[4];
      for (int i = 0; i < 4; ++i) {
        int m = wm * 64 + i * 16 + cc;
        int kg = (kc * 4 + q) ^ (m & 7);
        af[i] = *(const half8_t*)(As + m * 64 + kg * 8);
        int n = wn * 64 + i * 16 + cc;
        int kg2 = (kc * 4 + q) ^ (n & 7);
        bf[i] = *(const half8_t*)(Bs + n * 64 + kg2 * 8);
      }
      for (int i = 0; i < 4; ++i)
        for (int j2 = 0; j2 < 4; ++j2)
          acc[i][j2] = __builtin_amdgcn_mfma_f32_16x16x32_f16(af[i], bf[j2], acc[i][j2], 0, 0, 0);
    }
    __syncthreads();
  }
  for (int j2 = 0; j2 < 4; ++j2) {
    int n = n0 + wn * 64 + j2 * 16 + cc;
    float bv = bias[n];
    for (int i = 0; i < 4; ++i) {
      int mbase = m0 + wm * 64 + i * 16 + q * 4;
      for (int r = 0; r < 4; ++r)
        C[(size_t)(mbase + r) * GATES4 + n] = (_Float16)(acc[i][j2][r] + bv);
    }
  }
}

// ---------------- recurrence: 32 WGs, each owns 16 hidden cols ----------------
// wave wv = gate g (0=i,1=f,2=g,3=o). W_hh b-frags persistent in registers.
__global__ __launch_bounds__(256) void lstm_rec(
    const _Float16* __restrict__ xproj,  // [T*B][2048] fp16
    const _Float16* __restrict__ Whh,    // [2048][512] fp16
    _Float16* __restrict__ hbuf,         // [2][32*512] fp16 (zeroed)
    u32* __restrict__ flags,             // [32] (zeroed)
    _Float16* __restrict__ seqh,         // layer0: [T*B][512] fp16 out, else null
    float* __restrict__ outf) {          // layer1: d_out fp32, else null
  __shared__ _Float16 Hs[32 * 512];      // h_prev staged, swizzled
  __shared__ float Zs[4 * 32 * 17];      // [gate][b][hc] stride 17
  int wg = blockIdx.x;
  int tid = threadIdx.x, wv = tid >> 6, ln = tid & 63;
  int q = ln >> 4, hc = ln & 15;
  // persistent W fragments: B-operand row = gate*512 + wg*16 + (lane&15)
  half8_t wfrag[16];
  {
    const _Float16* wrow = Whh + (size_t)(wv * HID + wg * 16 + hc) * KDIM;
    for (int kc = 0; kc < 16; ++kc)
      wfrag[kc] = *(const half8_t*)(wrow + kc * 32 + q * 8);
  }
  float cst0 = 0.f, cst1 = 0.f;  // cell state for (b=tid>>4, hc=tid&15) and b+16
  for (int t = 1; t <= T_LEN; ++t) {
    // prefetch x_proj for this step (independent of flags)
    const _Float16* xp = xproj + (size_t)(t - 1) * BATCH * GATES4 + wv * HID + wg * 16 + hc;
    float xv[2][4];
    for (int mt = 0; mt < 2; ++mt)
      for (int r = 0; r < 4; ++r)
        xv[mt][r] = (float)xp[(size_t)(mt * 16 + q * 4 + r) * GATES4];
    if (t > 1) {
      u32 tgt = (u32)(t - 1);
      if (ln < 32) {
        while (__hip_atomic_load(&flags[ln], __ATOMIC_RELAXED, __HIP_MEMORY_SCOPE_AGENT) < tgt) {}
      }
      __threadfence();  // acquire: invalidate caches before reading others' h
    }
    const _Float16* hprev = hbuf + ((t - 1) & 1) * (BATCH * HID);
    for (int j = 0; j < 8; ++j) {  // stage 32KB h into LDS (swizzled)
      int p = (wv * 8 + j) * 64 + ln;
      int b = p >> 6, pc = p & 63, kg = pc ^ (b & 7);
      async_copy16(hprev + b * HID + kg * 8, (void*)(Hs + (p - ln) * 8));
    }
    __syncthreads();
    f32x4 acc0 = {}, acc1 = {};
    for (int kc = 0; kc < 16; ++kc) {
      int kg = kc * 4 + q;
      half8_t a0 = *(const half8_t*)(Hs + hc * 512 + (kg ^ (hc & 7)) * 8);
      half8_t a1 = *(const half8_t*)(Hs + (16 + hc) * 512 + (kg ^ ((16 + hc) & 7)) * 8);
      acc0 = __builtin_amdgcn_mfma_f32_16x16x32_f16(a0, wfrag[kc], acc0, 0, 0, 0);
      acc1 = __builtin_amdgcn_mfma_f32_16x16x32_f16(a1, wfrag[kc], acc1, 0, 0, 0);
    }
    for (int r = 0; r < 4; ++r) {
      Zs[wv * 544 + (q * 4 + r) * 17 + hc] = acc0[r] + xv[0][r];
      Zs[wv * 544 + (16 + q * 4 + r) * 17 + hc] = acc1[r] + xv[1][r];
    }
    __syncthreads();
    {
      int b = tid >> 4, h2 = tid & 15, b1 = b + 16;
      float zi0 = Zs[0 * 544 + b * 17 + h2], zf0 = Zs[1 * 544 + b * 17 + h2];
      float zg0 = Zs[2 * 544 + b * 17 + h2], zo0 = Zs[3 * 544 + b * 17 + h2];
      float zi1 = Zs[0 * 544 + b1 * 17 + h2], zf1 = Zs[1 * 544 + b1 * 17 + h2];
      float zg1 = Zs[2 * 544 + b1 * 17 + h2], zo1 = Zs[3 * 544 + b1 * 17 + h2];
      float i0 = 1.f / (1.f + __expf(-zi0)), f0 = 1.f / (1.f + __expf(-zf0));
      float g0 = tanhf(zg0), o0 = 1.f / (1.f + __expf(-zo0));
      float i1 = 1.f / (1.f + __expf(-zi1)), f1 = 1.f / (1.f + __expf(-zf1));
      float g1 = tanhf(zg1), o1 = 1.f / (1.f + __expf(-zo1));
      cst0 = f0 * cst0 + i0 * g0;
      cst1 = f1 * cst1 + i1 * g1;
      float hn0 = o0 * tanhf(cst0), hn1 = o1 * tanhf(cst1);
      int col = wg * 16 + h2;
      _Float16* hnext = hbuf + (t & 1) * (BATCH * HID);
      hnext[b * HID + col] = (_Float16)hn0;
      hnext[b1 * HID + col] = (_Float16)hn1;
      size_t so = (size_t)(t - 1) * BATCH * HID;
      if (seqh) {
        seqh[so + b * HID + col] = (_Float16)hn0;
        seqh[so + b1 * HID + col] = (_Float16)hn1;
      }
      if (outf) {
        outf[so + b * HID + col] = hn0;
        outf[so + b1 * HID + col] = hn1;
      }
    }
    __threadfence();  // release: make h stores visible device-wide
    __syncthreads();
    if (tid == 0)
      __hip_atomic_store(&flags[wg], (u32)t, __ATOMIC_RELEASE, __HIP_MEMORY_SCOPE_AGENT);
  }
}

extern "C" void kernel_launch(void* const* d_in, const int* in_sizes, int n_in,
                              void* d_out, int out_size, void* d_ws, size_t ws_size,
                              hipStream_t stream) {
  const float* x = (const float*)d_in[0];
  const float* Wih = (const float*)d_in[1];
  const float* Whh = (const float*)d_in[2];
  const float* bih = (const float*)d_in[3];
  const float* bhh = (const float*)d_in[4];
  char* ws = (char*)d_ws;
  // ws layout (bytes)
  const size_t OFF_XPROJ = 0;                       // 16384*2048*2 = 67108864
  const size_t OFF_X0H = 67108864;                  // 16777216
  const size_t OFF_H1SEQ = 83886080;                // 16777216
  const size_t OFF_WIHH = 100663296;                // 4194304
  const size_t OFF_WHHH = 104857600;                // 4194304
  const size_t OFF_BSUM = 109051904;                // 16384
  const size_t OFF_HBUF = 109068288;                // 65536
  const size_t OFF_FLAGS = 109133824;               // 128
  const size_t TOTAL = 109133952;
  if (ws_size < TOTAL) return;  // workspace too small -> visible failure
  _Float16* xproj = (_Float16*)(ws + OFF_XPROJ);
  _Float16* x0h = (_Float16*)(ws + OFF_X0H);
  _Float16* h1seq = (_Float16*)(ws + OFF_H1SEQ);
  _Float16* wihh = (_Float16*)(ws + OFF_WIHH);
  _Float16* whhh = (_Float16*)(ws + OFF_WHHH);
  float* bsum = (float*)(ws + OFF_BSUM);
  _Float16* hbuf = (_Float16*)(ws + OFF_HBUF);
  u32* flags = (u32*)(ws + OFF_FLAGS);

  hipMemsetAsync(ws + OFF_HBUF, 0, 65536 + 128, stream);
  convert_k<<<3072, 256, 0, stream>>>((const float4*)x, (const float4*)Wih,
                                      (const float4*)Whh, bih, bhh,
                                      (half4_t*)x0h, (half4_t*)wihh, (half4_t*)whhh, bsum);
  // layer 0
  gemm_xproj<<<2048, 256, 0, stream>>>(x0h, wihh, bsum, xproj);
  lstm_rec<<<32, 256, 0, stream>>>(xproj, whhh, hbuf, flags, h1seq, nullptr);
  // layer 1
  hipMemsetAsync(ws + OFF_HBUF, 0, 65536 + 128, stream);
  gemm_xproj<<<2048, 256, 0, stream>>>(h1seq, wihh + (size_t)GATES4 * KDIM,
                                       bsum + GATES4, xproj);
  lstm_rec<<<32, 256, 0, stream>>>(xproj, whhh + (size_t)GATES4 * KDIM, hbuf, flags,
                                   nullptr, (float*)d_out);
}

// Round 2
// 3697.786 us; speedup vs baseline: 2.3484x; 2.3484x over previous
//
#include <hip/hip_runtime.h>

// LSTM T=512, B=32, H=512, L=2. fp16 compute, fp32 accumulate/state.
// Single fused persistent kernel: 128 WGs x 128 thr (2 waves).
//   blocks 0..63  = layer 0 (x from x0h),
//   blocks 64..127= layer 1 (x = h0seq[t], pipelined on layer-0 flags).
// Each WG owns 8 hidden cols x 4 gates (n=32 per wave as 4 gates x 8 cols);
// wave wv covers batches [wv*16, wv*16+16). Weights live in registers.
// Sync: per-step flag per WG, relaxed agent atomics, write-through h stores,
// per-t unique slots => no fences / cache maintenance anywhere.

typedef _Float16 half8_t __attribute__((ext_vector_type(8)));
typedef _Float16 half4_t __attribute__((ext_vector_type(4)));
typedef float f32x4 __attribute__((ext_vector_type(4)));
typedef unsigned int u32;
typedef unsigned short u16;

#define T_LEN 512
#define BATCH 32
#define HID 512
#define SLOT 16384           // BATCH*HID elems per timestep slot
#define LW (2048 * 512)      // per-layer weight elems

__device__ __forceinline__ float fast_sigmoid(float x) {
  return 1.f / (1.f + __expf(-x));
}
__device__ __forceinline__ float fast_tanh(float x) {
  // 1 - 2/(1+e^{2x}); saturates correctly for |x| large (inf -> +/-1)
  return 1.f - 2.f / (1.f + __expf(2.f * x));
}

// ---------------- convert fp32 -> fp16 (x, Wih, Whh) + bias sum ----------------
__global__ __launch_bounds__(256) void convert_k(
    const float4* __restrict__ x,    // 8388608 floats = 2097152 float4
    const float4* __restrict__ wih,  // 2097152 floats = 524288 float4
    const float4* __restrict__ whh,  // same
    const float* __restrict__ bih, const float* __restrict__ bhh,
    half4_t* __restrict__ xh, half4_t* __restrict__ wihh, half4_t* __restrict__ whhh,
    float* __restrict__ bsum) {
  const int N4X = 2097152, N4W = 524288, TOT = N4X + 2 * N4W;
  int gid = blockIdx.x * 256 + threadIdx.x;
  for (int i = gid; i < TOT; i += gridDim.x * 256) {
    float4 v;
    half4_t* dst;
    if (i < N4X) { v = x[i]; dst = xh + i; }
    else if (i < N4X + N4W) { v = wih[i - N4X]; dst = wihh + (i - N4X); }
    else { v = whh[i - N4X - N4W]; dst = whhh + (i - N4X - N4W); }
    half4_t h;
    h[0] = (_Float16)v.x; h[1] = (_Float16)v.y; h[2] = (_Float16)v.z; h[3] = (_Float16)v.w;
    *dst = h;
  }
  if (gid < 4096) bsum[gid] = bih[gid] + bhh[gid];
}

// ---------------- fused 2-layer pipelined recurrence ----------------
__global__ __launch_bounds__(128, 1) void lstm_fused(
    const _Float16* __restrict__ x0h,   // [T][SLOT]
    const _Float16* __restrict__ wih16, // [2][2048][512]
    const _Float16* __restrict__ whh16, // [2][2048][512]
    const float* __restrict__ bsum,     // [2][2048]
    _Float16* h0seq,                    // [T+1][SLOT], slot0 zeroed
    _Float16* h1seq,                    // [T+1][SLOT], slot0 zeroed
    u32* flags0, u32* flags1,           // [64] each, zeroed
    float* outf) {                      // [T][B][H] fp32
  int bid = blockIdx.x;
  int layer = bid >> 6, wg = bid & 63;
  int tid = threadIdx.x;               // 0..127
  int ln = tid & 63;
  int q = ln >> 4, l15 = ln & 15;
  int m0 = (tid >> 6) * 16;            // wave's batch base

  // ---- persistent register weight fragments: n=32 = 4 gates x 8 cols ----
  const _Float16* wih_l = wih16 + (size_t)layer * LW;
  const _Float16* whh_l = whh16 + (size_t)layer * LW;
  half8_t wx[2][16], wh[2][16];
  float bv[2];
#pragma unroll
  for (int j = 0; j < 2; ++j) {
    int nl = j * 16 + l15;
    int grow = (nl >> 3) * 512 + wg * 8 + (nl & 7);   // gate*512 + col
    size_t ro = (size_t)grow * 512;
#pragma unroll
    for (int kc = 0; kc < 16; ++kc) {
      wx[j][kc] = *(const half8_t*)(wih_l + ro + kc * 32 + q * 8);
      wh[j][kc] = *(const half8_t*)(whh_l + ro + kc * 32 + q * 8);
    }
    bv[j] = bsum[layer * 2048 + grow];
  }

  const _Float16* xbase = layer ? (h0seq + SLOT) : x0h;  // step t reads xbase+(t-1)*SLOT
  _Float16* hself = layer ? h1seq : h0seq;
  u32* fself = layer ? flags1 : flags0;

  // consumer mapping: thread -> (batch cb, col pair cp)
  int cb = tid >> 2;
  int cp = tid & 3;
  int col0 = wg * 8 + cp * 2;
  float cst0 = 0.f, cst1 = 0.f;

  __shared__ float Zs[4 * 297];  // [gate]*297 + b*9 + c   (33*9 per gate)

  for (int t = 1; t <= T_LEN; ++t) {
    const _Float16* xsrc = xbase + (size_t)(t - 1) * SLOT;
    const _Float16* hsrc = hself + (size_t)(t - 1) * SLOT;
    f32x4 acc0 = {}, acc1 = {};
    half8_t af[16];

    if (layer == 0) {
      // x-part: independent of flags — do before waiting
#pragma unroll
      for (int kc = 0; kc < 16; ++kc)
        af[kc] = *(const half8_t*)(xsrc + (m0 + l15) * HID + kc * 32 + q * 8);
#pragma unroll
      for (int kc = 0; kc < 16; ++kc) {
        acc0 = __builtin_amdgcn_mfma_f32_16x16x32_f16(af[kc], wx[0][kc], acc0, 0, 0, 0);
        acc1 = __builtin_amdgcn_mfma_f32_16x16x32_f16(af[kc], wx[1][kc], acc1, 0, 0, 0);
      }
      u32 tgt = (u32)(t - 1);
      while (__hip_atomic_load(&fself[ln], __ATOMIC_RELAXED, __HIP_MEMORY_SCOPE_AGENT) < tgt) {
        __builtin_amdgcn_s_sleep(1);
      }
      asm volatile("" ::: "memory");
    } else {
      // wait for layer-0 step t, then x-part from h0seq[t]
      u32 tgt = (u32)t;
      while (__hip_atomic_load(&flags0[ln], __ATOMIC_RELAXED, __HIP_MEMORY_SCOPE_AGENT) < tgt) {
        __builtin_amdgcn_s_sleep(1);
      }
      asm volatile("" ::: "memory");
#pragma unroll
      for (int kc = 0; kc < 16; ++kc)
        af[kc] = *(const half8_t*)(xsrc + (m0 + l15) * HID + kc * 32 + q * 8);
#pragma unroll
      for (int kc = 0; kc < 16; ++kc) {
        acc0 = __builtin_amdgcn_mfma_f32_16x16x32_f16(af[kc], wx[0][kc], acc0, 0, 0, 0);
        acc1 = __builtin_amdgcn_mfma_f32_16x16x32_f16(af[kc], wx[1][kc], acc1, 0, 0, 0);
      }
      u32 tgt1 = (u32)(t - 1);
      while (__hip_atomic_load(&flags1[ln], __ATOMIC_RELAXED, __HIP_MEMORY_SCOPE_AGENT) < tgt1) {
        __builtin_amdgcn_s_sleep(1);
      }
      asm volatile("" ::: "memory");
    }

    // h-part
#pragma unroll
    for (int kc = 0; kc < 16; ++kc)
      af[kc] = *(const half8_t*)(hsrc + (m0 + l15) * HID + kc * 32 + q * 8);
#pragma unroll
    for (int kc = 0; kc < 16; ++kc) {
      acc0 = __builtin_amdgcn_mfma_f32_16x16x32_f16(af[kc], wh[0][kc], acc0, 0, 0, 0);
      acc1 = __builtin_amdgcn_mfma_f32_16x16x32_f16(af[kc], wh[1][kc], acc1, 0, 0, 0);
    }

    // publish z to LDS: lane's tile j col = nl = j*16+l15 -> gate=nl>>3, c=nl&7
#pragma unroll
    for (int j = 0; j < 2; ++j) {
      int nl = j * 16 + l15, g = nl >> 3, c = nl & 7;
      const f32x4& a = j ? acc1 : acc0;
#pragma unroll
      for (int r = 0; r < 4; ++r)
        Zs[g * 297 + (m0 + q * 4 + r) * 9 + c] = a[r] + bv[j];
    }
    __syncthreads();

    // elementwise: thread owns (cb, col0, col0+1)
    {
      float zi0 = Zs[0 * 297 + cb * 9 + cp * 2], zi1 = Zs[0 * 297 + cb * 9 + cp * 2 + 1];
      float zf0 = Zs[1 * 297 + cb * 9 + cp * 2], zf1 = Zs[1 * 297 + cb * 9 + cp * 2 + 1];
      float zg0 = Zs[2 * 297 + cb * 9 + cp * 2], zg1 = Zs[2 * 297 + cb * 9 + cp * 2 + 1];
      float zo0 = Zs[3 * 297 + cb * 9 + cp * 2], zo1 = Zs[3 * 297 + cb * 9 + cp * 2 + 1];
      float i0 = fast_sigmoid(zi0), f0 = fast_sigmoid(zf0), g0 = fast_tanh(zg0), o0 = fast_sigmoid(zo0);
      float i1 = fast_sigmoid(zi1), f1 = fast_sigmoid(zf1), g1 = fast_tanh(zg1), o1 = fast_sigmoid(zo1);
      cst0 = f0 * cst0 + i0 * g0;
      cst1 = f1 * cst1 + i1 * g1;
      float h0 = o0 * fast_tanh(cst0);
      float h1 = o1 * fast_tanh(cst1);
      // write-through packed h store (visible at L3 before flag)
      u32 hp = (u32)__builtin_bit_cast(u16, (_Float16)h0) |
               ((u32)__builtin_bit_cast(u16, (_Float16)h1) << 16);
      u32* hdst = (u32*)(hself + (size_t)t * SLOT + cb * HID + col0);
      __hip_atomic_store(hdst, hp, __ATOMIC_RELAXED, __HIP_MEMORY_SCOPE_AGENT);
      if (layer) {
        float2 o2; o2.x = h0; o2.y = h1;
        *(float2*)(outf + (size_t)(t - 1) * SLOT + cb * HID + col0) = o2;
      }
    }
    // __syncthreads drains each thread's vmcnt (incl. the h store) before barrier
    __syncthreads();
    if (tid == 0)
      __hip_atomic_store(&fself[wg], (u32)t, __ATOMIC_RELAXED, __HIP_MEMORY_SCOPE_AGENT);
  }
}

extern "C" void kernel_launch(void* const* d_in, const int* in_sizes, int n_in,
                              void* d_out, int out_size, void* d_ws, size_t ws_size,
                              hipStream_t stream) {
  const float* x = (const float*)d_in[0];
  const float* Wih = (const float*)d_in[1];
  const float* Whh = (const float*)d_in[2];
  const float* bih = (const float*)d_in[3];
  const float* bhh = (const float*)d_in[4];
  char* ws = (char*)d_ws;
  // ws layout (bytes)
  const size_t OFF_X0H = 0;                  // 16,777,216
  const size_t OFF_H0SEQ = 16777216;         // 513*32768 = 16,809,984
  const size_t OFF_H1SEQ = 33587200;         // 16,809,984
  const size_t OFF_WIH = 50397184;           // 4,194,304
  const size_t OFF_WHH = 54591488;           // 4,194,304
  const size_t OFF_BSUM = 58785792;          // 16,384
  const size_t OFF_FLAGS0 = 58802176;        // 256
  const size_t OFF_FLAGS1 = 58802432;        // 256
  const size_t TOTAL = 58802688;
  if (ws_size < TOTAL) return;
  _Float16* x0h = (_Float16*)(ws + OFF_X0H);
  _Float16* h0seq = (_Float16*)(ws + OFF_H0SEQ);
  _Float16* h1seq = (_Float16*)(ws + OFF_H1SEQ);
  _Float16* wihh = (_Float16*)(ws + OFF_WIH);
  _Float16* whhh = (_Float16*)(ws + OFF_WHH);
  float* bsum = (float*)(ws + OFF_BSUM);
  u32* flags0 = (u32*)(ws + OFF_FLAGS0);
  u32* flags1 = (u32*)(ws + OFF_FLAGS1);

  // zero: flags + slot0 of both h sequences
  hipMemsetAsync(ws + OFF_FLAGS0, 0, 512, stream);
  hipMemsetAsync(ws + OFF_H0SEQ, 0, 32768, stream);
  hipMemsetAsync(ws + OFF_H1SEQ, 0, 32768, stream);
  convert_k<<<3072, 256, 0, stream>>>((const float4*)x, (const float4*)Wih,
                                      (const float4*)Whh, bih, bhh,
                                      (half4_t*)x0h, (half4_t*)wihh, (half4_t*)whhh, bsum);
  lstm_fused<<<128, 128, 0, stream>>>(x0h, wihh, whhh, bsum, h0seq, h1seq,
                                      flags0, flags1, (float*)d_out);
}

// Round 3
// 3388.350 us; speedup vs baseline: 2.5629x; 1.0913x over previous
//
#include <hip/hip_runtime.h>

// LSTM T=512, B=32, H=512, L=2. fp16 compute, fp32 accumulate/state.
// Single fused persistent kernel: 128 WGs x 128 thr (2 waves).
//   blocks 0..63  = layer 0 (x from x0h),
//   blocks 64..127= layer 1 (x = h0seq[t], pipelined on layer-0 epoch).
// Each WG owns 8 hidden cols x 4 gates (n=32 per wave as 4 gates x 8 cols);
// wave wv covers batches [wv*16, wv*16+16). Weights live in registers.
// Sync: ONE epoch counter per layer (own cache line). Producers publish via
// relaxed agent atomicAdd(+1) after a vmcnt-drained barrier; "all WGs done
// step s" <=> epoch >= 64*s. Consumers poll a single uniform address with
// L2-bypassing atomic loads. Write-through h stores + per-t unique slots
// => no fences / cache maintenance anywhere.

typedef _Float16 half8_t __attribute__((ext_vector_type(8)));
typedef _Float16 half4_t __attribute__((ext_vector_type(4)));
typedef float f32x4 __attribute__((ext_vector_type(4)));
typedef unsigned int u32;
typedef unsigned short u16;

#define T_LEN 512
#define BATCH 32
#define HID 512
#define SLOT 16384           // BATCH*HID elems per timestep slot
#define LW (2048 * 512)      // per-layer weight elems

__device__ __forceinline__ float fast_sigmoid(float x) {
  return 1.f / (1.f + __expf(-x));
}
__device__ __forceinline__ float fast_tanh(float x) {
  return 1.f - 2.f / (1.f + __expf(2.f * x));
}
__device__ __forceinline__ u32 epoch_peek(const u32* p) {
  return __hip_atomic_load(p, __ATOMIC_RELAXED, __HIP_MEMORY_SCOPE_AGENT);
}

// ---------------- convert fp32 -> fp16 (x, Wih, Whh) + bias sum ----------------
__global__ __launch_bounds__(256) void convert_k(
    const float4* __restrict__ x,    // 8388608 floats = 2097152 float4
    const float4* __restrict__ wih,  // 2097152 floats = 524288 float4
    const float4* __restrict__ whh,  // same
    const float* __restrict__ bih, const float* __restrict__ bhh,
    half4_t* __restrict__ xh, half4_t* __restrict__ wihh, half4_t* __restrict__ whhh,
    float* __restrict__ bsum) {
  const int N4X = 2097152, N4W = 524288, TOT = N4X + 2 * N4W;
  int gid = blockIdx.x * 256 + threadIdx.x;
  for (int i = gid; i < TOT; i += gridDim.x * 256) {
    float4 v;
    half4_t* dst;
    if (i < N4X) { v = x[i]; dst = xh + i; }
    else if (i < N4X + N4W) { v = wih[i - N4X]; dst = wihh + (i - N4X); }
    else { v = whh[i - N4X - N4W]; dst = whhh + (i - N4X - N4W); }
    half4_t h;
    h[0] = (_Float16)v.x; h[1] = (_Float16)v.y; h[2] = (_Float16)v.z; h[3] = (_Float16)v.w;
    *dst = h;
  }
  if (gid < 4096) bsum[gid] = bih[gid] + bhh[gid];
}

// ---------------- fused 2-layer pipelined recurrence ----------------
__global__ __launch_bounds__(128, 1) void lstm_fused(
    const _Float16* __restrict__ x0h,   // [T][SLOT]
    const _Float16* __restrict__ wih16, // [2][2048][512]
    const _Float16* __restrict__ whh16, // [2][2048][512]
    const float* __restrict__ bsum,     // [2][2048]
    _Float16* h0seq,                    // [T+1][SLOT], slot0 zeroed
    _Float16* h1seq,                    // [T+1][SLOT], slot0 zeroed
    u32* epoch0, u32* epoch1,           // 1 counter each, own cache line, zeroed
    float* outf) {                      // [T][B][H] fp32
  int bid = blockIdx.x;
  int layer = bid >> 6, wg = bid & 63;
  int tid = threadIdx.x;               // 0..127
  int ln = tid & 63;
  int q = ln >> 4, l15 = ln & 15;
  int m0 = (tid >> 6) * 16;            // wave's batch base

  // ---- persistent register weight fragments: n=32 = 4 gates x 8 cols ----
  const _Float16* wih_l = wih16 + (size_t)layer * LW;
  const _Float16* whh_l = whh16 + (size_t)layer * LW;
  half8_t wx[2][16], wh[2][16];
  float bv[2];
#pragma unroll
  for (int j = 0; j < 2; ++j) {
    int nl = j * 16 + l15;
    int grow = (nl >> 3) * 512 + wg * 8 + (nl & 7);   // gate*512 + col
    size_t ro = (size_t)grow * 512;
#pragma unroll
    for (int kc = 0; kc < 16; ++kc) {
      wx[j][kc] = *(const half8_t*)(wih_l + ro + kc * 32 + q * 8);
      wh[j][kc] = *(const half8_t*)(whh_l + ro + kc * 32 + q * 8);
    }
    bv[j] = bsum[layer * 2048 + grow];
  }

  const _Float16* xbase = layer ? (h0seq + SLOT) : x0h;  // step t reads xbase+(t-1)*SLOT
  _Float16* hself = layer ? h1seq : h0seq;
  u32* eself = layer ? epoch1 : epoch0;

  // consumer mapping: thread -> (batch cb, col pair cp)
  int cb = tid >> 2;
  int cp = tid & 3;
  int col0 = wg * 8 + cp * 2;
  float cst0 = 0.f, cst1 = 0.f;

  __shared__ float Zs[4 * 297];  // [gate]*297 + b*9 + c   (33*9 per gate)

  for (int t = 1; t <= T_LEN; ++t) {
    const _Float16* xsrc = xbase + (size_t)(t - 1) * SLOT;
    const _Float16* hsrc = hself + (size_t)(t - 1) * SLOT;
    f32x4 acc0 = {}, acc1 = {};
    half8_t af[16];

    if (layer == 0) {
      // x-part: independent of sync — do before waiting
#pragma unroll
      for (int kc = 0; kc < 16; ++kc)
        af[kc] = *(const half8_t*)(xsrc + (m0 + l15) * HID + kc * 32 + q * 8);
#pragma unroll
      for (int kc = 0; kc < 16; ++kc) {
        acc0 = __builtin_amdgcn_mfma_f32_16x16x32_f16(af[kc], wx[0][kc], acc0, 0, 0, 0);
        acc1 = __builtin_amdgcn_mfma_f32_16x16x32_f16(af[kc], wx[1][kc], acc1, 0, 0, 0);
      }
      u32 tgt = 64u * (u32)(t - 1);
      while (epoch_peek(epoch0) < tgt) { __builtin_amdgcn_s_sleep(1); }
      asm volatile("" ::: "memory");
    } else {
      // need: layer-0 all done step t (x = h0seq[t]) AND own layer done t-1
      u32 tgt0 = 64u * (u32)t, tgt1 = 64u * (u32)(t - 1);
      while (epoch_peek(epoch0) < tgt0 || epoch_peek(epoch1) < tgt1) {
        __builtin_amdgcn_s_sleep(1);
      }
      asm volatile("" ::: "memory");
#pragma unroll
      for (int kc = 0; kc < 16; ++kc)
        af[kc] = *(const half8_t*)(xsrc + (m0 + l15) * HID + kc * 32 + q * 8);
#pragma unroll
      for (int kc = 0; kc < 16; ++kc) {
        acc0 = __builtin_amdgcn_mfma_f32_16x16x32_f16(af[kc], wx[0][kc], acc0, 0, 0, 0);
        acc1 = __builtin_amdgcn_mfma_f32_16x16x32_f16(af[kc], wx[1][kc], acc1, 0, 0, 0);
      }
    }

    // h-part
#pragma unroll
    for (int kc = 0; kc < 16; ++kc)
      af[kc] = *(const half8_t*)(hsrc + (m0 + l15) * HID + kc * 32 + q * 8);
#pragma unroll
    for (int kc = 0; kc < 16; ++kc) {
      acc0 = __builtin_amdgcn_mfma_f32_16x16x32_f16(af[kc], wh[0][kc], acc0, 0, 0, 0);
      acc1 = __builtin_amdgcn_mfma_f32_16x16x32_f16(af[kc], wh[1][kc], acc1, 0, 0, 0);
    }

    // publish z to LDS: lane's tile j col = nl = j*16+l15 -> gate=nl>>3, c=nl&7
#pragma unroll
    for (int j = 0; j < 2; ++j) {
      int nl = j * 16 + l15, g = nl >> 3, c = nl & 7;
      const f32x4& a = j ? acc1 : acc0;
#pragma unroll
      for (int r = 0; r < 4; ++r)
        Zs[g * 297 + (m0 + q * 4 + r) * 9 + c] = a[r] + bv[j];
    }
    __syncthreads();

    // elementwise: thread owns (cb, col0, col0+1)
    float h0, h1;
    {
      float zi0 = Zs[0 * 297 + cb * 9 + cp * 2], zi1 = Zs[0 * 297 + cb * 9 + cp * 2 + 1];
      float zf0 = Zs[1 * 297 + cb * 9 + cp * 2], zf1 = Zs[1 * 297 + cb * 9 + cp * 2 + 1];
      float zg0 = Zs[2 * 297 + cb * 9 + cp * 2], zg1 = Zs[2 * 297 + cb * 9 + cp * 2 + 1];
      float zo0 = Zs[3 * 297 + cb * 9 + cp * 2], zo1 = Zs[3 * 297 + cb * 9 + cp * 2 + 1];
      float i0 = fast_sigmoid(zi0), f0 = fast_sigmoid(zf0), g0 = fast_tanh(zg0), o0 = fast_sigmoid(zo0);
      float i1 = fast_sigmoid(zi1), f1 = fast_sigmoid(zf1), g1 = fast_tanh(zg1), o1 = fast_sigmoid(zo1);
      cst0 = f0 * cst0 + i0 * g0;
      cst1 = f1 * cst1 + i1 * g1;
      h0 = o0 * fast_tanh(cst0);
      h1 = o1 * fast_tanh(cst1);
      // write-through packed h store (retires at coherence point; drained by
      // the __syncthreads below before the epoch publish)
      u32 hp = (u32)__builtin_bit_cast(u16, (_Float16)h0) |
               ((u32)__builtin_bit_cast(u16, (_Float16)h1) << 16);
      u32* hdst = (u32*)(hself + (size_t)t * SLOT + cb * HID + col0);
      __hip_atomic_store(hdst, hp, __ATOMIC_RELAXED, __HIP_MEMORY_SCOPE_AGENT);
    }
    // drains each thread's vmcnt (incl. the h store) before the publish
    __syncthreads();
    if (tid == 0)
      (void)__hip_atomic_fetch_add(eself, 1u, __ATOMIC_RELAXED, __HIP_MEMORY_SCOPE_AGENT);
    // out store AFTER publish — nobody consumes it; drain overlaps next step
    if (layer) {
      float2 o2; o2.x = h0; o2.y = h1;
      *(float2*)(outf + (size_t)(t - 1) * SLOT + cb * HID + col0) = o2;
    }
  }
}

extern "C" void kernel_launch(void* const* d_in, const int* in_sizes, int n_in,
                              void* d_out, int out_size, void* d_ws, size_t ws_size,
                              hipStream_t stream) {
  const float* x = (const float*)d_in[0];
  const float* Wih = (const float*)d_in[1];
  const float* Whh = (const float*)d_in[2];
  const float* bih = (const float*)d_in[3];
  const float* bhh = (const float*)d_in[4];
  char* ws = (char*)d_ws;
  // ws layout (bytes)
  const size_t OFF_X0H = 0;                  // 16,777,216
  const size_t OFF_H0SEQ = 16777216;         // 513*32768 = 16,809,984
  const size_t OFF_H1SEQ = 33587200;         // 16,809,984
  const size_t OFF_WIH = 50397184;           // 4,194,304
  const size_t OFF_WHH = 54591488;           // 4,194,304
  const size_t OFF_BSUM = 58785792;          // 16,384
  const size_t OFF_EPOCH0 = 58802176;        // own cache line
  const size_t OFF_EPOCH1 = 58802432;        // own cache line (+256B)
  const size_t TOTAL = 58802688;
  if (ws_size < TOTAL) return;
  _Float16* x0h = (_Float16*)(ws + OFF_X0H);
  _Float16* h0seq = (_Float16*)(ws + OFF_H0SEQ);
  _Float16* h1seq = (_Float16*)(ws + OFF_H1SEQ);
  _Float16* wihh = (_Float16*)(ws + OFF_WIH);
  _Float16* whhh = (_Float16*)(ws + OFF_WHH);
  float* bsum = (float*)(ws + OFF_BSUM);
  u32* epoch0 = (u32*)(ws + OFF_EPOCH0);
  u32* epoch1 = (u32*)(ws + OFF_EPOCH1);

  // zero: epochs + slot0 of both h sequences
  hipMemsetAsync(ws + OFF_EPOCH0, 0, 512, stream);
  hipMemsetAsync(ws + OFF_H0SEQ, 0, 32768, stream);
  hipMemsetAsync(ws + OFF_H1SEQ, 0, 32768, stream);
  convert_k<<<3072, 256, 0, stream>>>((const float4*)x, (const float4*)Wih,
                                      (const float4*)Whh, bih, bhh,
                                      (half4_t*)x0h, (half4_t*)wihh, (half4_t*)whhh, bsum);
  lstm_fused<<<128, 128, 0, stream>>>(x0h, wihh, whhh, bsum, h0seq, h1seq,
                                      epoch0, epoch1, (float*)d_out);
}